// Round 1
// baseline (166.417 us; speedup 1.0000x reference)
//
#include <hip/hip_runtime.h>
#include <math.h>

#define F 128
#define H 64       // F/2
#define NBMOL 48
#define A 8        // atoms per block in atom kernel
#define CAP 768    // LDS chunk capacity in pair kernel
#define SPLIT 8    // blocks per molecule in pair kernel

__device__ __forceinline__ float silu_f(float x) {
    return x / (1.0f + __expf(-x));
}
__device__ __forceinline__ float softplus_f(float x) {
    return fmaxf(x, 0.0f) + log1pf(__expf(-fabsf(x)));
}
__device__ __forceinline__ float frcp(float x) {
    return __builtin_amdgcn_rcpf(x);
}

// Kernel A: per-atom MLPs (q, c6, mu) + segment sums + segment boundaries.
// One wave (64 threads) handles A=8 atoms. lane j owns hidden unit j of both
// MLPs; h0 tile is staged transposed in LDS so the inner loop reads the 8
// atoms' activations as two ds_read_b128 (wave-uniform address -> broadcast).
__global__ __launch_bounds__(64) void k_atom(
    const float* __restrict__ h0, const float* __restrict__ h1,
    const int* __restrict__ batch,
    const float* __restrict__ qW1, const float* __restrict__ qb1,
    const float* __restrict__ qW2, const float* __restrict__ qb2,
    const float* __restrict__ cW1, const float* __restrict__ cb1,
    const float* __restrict__ cW2, const float* __restrict__ cb2,
    const float* __restrict__ muW,
    float* __restrict__ q_raw, float* __restrict__ sqc6,
    float* __restrict__ mu,
    float* __restrict__ qsum, float* __restrict__ cnt,
    int* __restrict__ segstart, int* __restrict__ segend, int N)
{
    const int lane = threadIdx.x;
    const int a0 = blockIdx.x * A;
    __shared__ float sh[F * A];   // transposed: sh[f*A + a]

    for (int k = lane; k < A * F; k += 64) {
        int idx = a0 * F + k;
        float v = (idx < N * F) ? h0[idx] : 0.0f;
        int a = k >> 7, f = k & (F - 1);
        sh[f * A + a] = v;
    }
    __syncthreads();

    float accq[A], accc[A];
    const float bq = qb1[lane], bc = cb1[lane];
    #pragma unroll
    for (int a = 0; a < A; ++a) { accq[a] = bq; accc[a] = bc; }

    for (int f = 0; f < F; ++f) {
        float wq = qW1[f * H + lane];
        float wc = cW1[f * H + lane];
        const float* s = &sh[f * A];
        #pragma unroll
        for (int a = 0; a < A; ++a) {
            float hv = s[a];
            accq[a] = fmaf(hv, wq, accq[a]);
            accc[a] = fmaf(hv, wc, accc[a]);
        }
    }

    const float w2q = qW2[lane], w2c = cW2[lane];
    float pq[A], pc[A];
    #pragma unroll
    for (int a = 0; a < A; ++a) {
        pq[a] = silu_f(accq[a]) * w2q;
        pc[a] = silu_f(accc[a]) * w2c;
    }

    // dipole partials: mu[i][d] = sum_f h1[i,d,f] * muW[f]
    const float mw0 = muW[lane], mw1 = muW[lane + 64];
    float pm[A][3];
    #pragma unroll
    for (int a = 0; a < A; ++a) {
        int i = a0 + a;
        if (i < N) {
            #pragma unroll
            for (int d = 0; d < 3; ++d) {
                const float* row = &h1[((size_t)i * 3 + d) * F];
                pm[a][d] = fmaf(row[lane], mw0, row[lane + 64] * mw1);
            }
        } else {
            pm[a][0] = pm[a][1] = pm[a][2] = 0.0f;
        }
    }

    // butterfly reductions over the 64-lane wave (all lanes end with the sum)
    #pragma unroll
    for (int off = 32; off > 0; off >>= 1) {
        #pragma unroll
        for (int a = 0; a < A; ++a) {
            pq[a]    += __shfl_xor(pq[a], off);
            pc[a]    += __shfl_xor(pc[a], off);
            pm[a][0] += __shfl_xor(pm[a][0], off);
            pm[a][1] += __shfl_xor(pm[a][1], off);
            pm[a][2] += __shfl_xor(pm[a][2], off);
        }
    }

    const float qb2v = qb2[0], cb2v = cb2[0];
    #pragma unroll
    for (int a = 0; a < A; ++a) {
        if (lane == a) {
            int i = a0 + a;
            if (i < N) {
                float qv = pq[a] + qb2v;
                q_raw[i] = qv;
                float c6 = softplus_f(pc[a] + cb2v);
                sqc6[i] = sqrtf(c6);
                mu[i * 3 + 0] = pm[a][0];
                mu[i * 3 + 1] = pm[a][1];
                mu[i * 3 + 2] = pm[a][2];
                int b = batch[i];
                atomicAdd(&qsum[b], qv);
                atomicAdd(&cnt[b], 1.0f);
                if (i == 0 || batch[i - 1] != b) segstart[b] = i;
                if (i == N - 1 || batch[i + 1] != b) segend[b] = i + 1;
            }
        }
    }
}

// Kernel B: pairwise energy. Grid (NBMOL, SPLIT); block 256 = 16 row-slots x
// 16 col-lanes. Molecule staged as SoA in LDS (conflict-free ds_read_b32).
__global__ __launch_bounds__(256) void k_pair(
    const float* __restrict__ pos,
    const float* __restrict__ q_raw, const float* __restrict__ sqc6,
    const float* __restrict__ mu,
    const float* __restrict__ qsum, const float* __restrict__ cnt,
    const int* __restrict__ segstart, const int* __restrict__ segend,
    float* __restrict__ out)
{
    const int b = blockIdx.x;
    const int s = blockIdx.y;
    const int st = segstart[b];
    const int n = segend[b] - st;
    const int tid = threadIdx.x;

    __shared__ float sq[CAP], sc[CAP], sx[CAP], sy[CAP], sz[CAP];
    __shared__ float smx[CAP], smy[CAP], smz[CAP];
    __shared__ float red[4];

    float e_c = 0.f, e_v = 0.f, e_d = 0.f;

    if (n > 1) {
        const float mean = qsum[b] / fmaxf(cnt[b], 1.0f);
        const int r = tid >> 4;   // row slot 0..15
        const int c = tid & 15;   // col lane 0..15
        for (int j0 = 0; j0 < n; j0 += CAP) {   // chunked: correct for any n
            const int chunk = min(CAP, n - j0);
            __syncthreads();
            for (int k = tid; k < chunk; k += 256) {
                int j = st + j0 + k;
                sq[k]  = q_raw[j] - mean;
                sc[k]  = sqc6[j];
                sx[k]  = pos[j * 3 + 0];
                sy[k]  = pos[j * 3 + 1];
                sz[k]  = pos[j * 3 + 2];
                smx[k] = mu[j * 3 + 0];
                smy[k] = mu[j * 3 + 1];
                smz[k] = mu[j * 3 + 2];
            }
            __syncthreads();
            const float mean_l = mean;
            for (int il = s + SPLIT * r; il < n; il += SPLIT * 16) {
                const int i = st + il;
                const float qi  = q_raw[i] - mean_l;
                const float sci = sqc6[i];
                const float xi = pos[i * 3], yi = pos[i * 3 + 1], zi = pos[i * 3 + 2];
                const float mxi = mu[i * 3], myi = mu[i * 3 + 1], mzi = mu[i * 3 + 2];
                for (int jl = c; jl < chunk; jl += 16) {
                    if (j0 + jl == il) continue;   // diagonal
                    float dx = xi - sx[jl], dy = yi - sy[jl], dz = zi - sz[jl];
                    float ds0 = fmaf(dx, dx, fmaf(dy, dy, dz * dz)); // dist_sq (no eps)
                    float d   = sqrtf(ds0 + 1e-8f);                  // dist (with eps)
                    float inv_d = frcp(d);
                    // Coulomb: q_i q_j / d * (1 - exp(-d/2))
                    e_c = fmaf(qi * sq[jl] * inv_d, 1.0f - __expf(-0.5f * d), e_c);
                    // vdW: sqrt(c6_i c6_j) / (dist_sq^3 + 20)
                    float r6 = ds0 * ds0 * ds0;
                    e_v = fmaf(sci * sc[jl], frcp(r6 + 20.0f), e_v);
                    // dipole-dipole
                    float mdm  = fmaf(mxi, smx[jl], fmaf(myi, smy[jl], mzi * smz[jl]));
                    float mdni = fmaf(mxi, dx, fmaf(myi, dy, mzi * dz)) * inv_d;
                    float mdnj = fmaf(smx[jl], dx, fmaf(smy[jl], dy, smz[jl] * dz)) * inv_d;
                    e_d = fmaf(mdm - 3.0f * mdni * mdnj,
                               frcp(fmaf(ds0, d, 10.0f)), e_d);
                }
            }
        }
    }

    // energy = 0.5*14.399*E_coul - 0.5*E_vdw_mag + 0.5*E_dip
    float v = fmaf(7.1995f, e_c, fmaf(-0.5f, e_v, 0.5f * e_d));
    #pragma unroll
    for (int off = 32; off > 0; off >>= 1) v += __shfl_xor(v, off);
    __syncthreads();
    if ((tid & 63) == 0) red[tid >> 6] = v;
    __syncthreads();
    if (tid == 0) atomicAdd(out, red[0] + red[1] + red[2] + red[3]);
}

extern "C" void kernel_launch(void* const* d_in, const int* in_sizes, int n_in,
                              void* d_out, int out_size, void* d_ws, size_t ws_size,
                              hipStream_t stream) {
    const float* h0  = (const float*)d_in[0];
    const float* h1  = (const float*)d_in[1];
    const float* pos = (const float*)d_in[2];
    const int*   batch = (const int*)d_in[3];
    const float* qW1 = (const float*)d_in[4];
    const float* qb1 = (const float*)d_in[5];
    const float* qW2 = (const float*)d_in[6];
    const float* qb2 = (const float*)d_in[7];
    const float* cW1 = (const float*)d_in[8];
    const float* cb1 = (const float*)d_in[9];
    const float* cW2 = (const float*)d_in[10];
    const float* cb2 = (const float*)d_in[11];
    const float* muW = (const float*)d_in[12];
    float* out = (float*)d_out;
    const int N = in_sizes[0] / F;

    // workspace layout (floats): [qsum 48 | cnt 48 | segstart 48 | segend 48 |
    //                             pad to 256 | q_raw N | sqc6 N | mu 3N]
    float* ws = (float*)d_ws;
    float* qsum = ws;
    float* cnt  = ws + 48;
    int* segstart = (int*)(ws + 96);
    int* segend   = (int*)(ws + 144);
    float* q_raw = ws + 256;
    float* sqc6  = q_raw + N;
    float* mu    = sqc6 + N;

    // ws header + out are re-poisoned to 0xAA before every timed launch
    hipMemsetAsync(ws, 0, 192 * sizeof(float), stream);
    hipMemsetAsync(out, 0, sizeof(float), stream);

    int nblk = (N + A - 1) / A;
    k_atom<<<nblk, 64, 0, stream>>>(h0, h1, batch, qW1, qb1, qW2, qb2,
                                    cW1, cb1, cW2, cb2, muW,
                                    q_raw, sqc6, mu, qsum, cnt,
                                    segstart, segend, N);
    k_pair<<<dim3(NBMOL, SPLIT), 256, 0, stream>>>(pos, q_raw, sqc6, mu,
                                                   qsum, cnt, segstart, segend,
                                                   out);
}